// Round 12
// baseline (347.010 us; speedup 1.0000x reference)
//
#include <hip/hip_runtime.h>
#include <cstdint>
#include <cstddef>

#define TSEQ   2048
#define BATCH  2
#define BT     4096      // BATCH*TSEQ
#define DMODEL 1024
#define NHEADS 16
#define HDIM   64
#define FFDIM  4096
#define QKVS   3072      // row stride of fused qkv buffer

typedef __attribute__((ext_vector_type(8))) short short8;    // 8 bf16 = 4 VGPRs
typedef __attribute__((ext_vector_type(4))) float floatx4;   // MFMA acc
typedef unsigned short us;

__device__ __forceinline__ float bf2f(us u) {
    union { unsigned int i; float f; } v; v.i = ((unsigned int)u) << 16; return v.f;
}
__device__ __forceinline__ us f2bf(float f) {
    union { float f; unsigned int i; } v; v.f = f;
    unsigned int r = v.i + 0x7fffu + ((v.i >> 16) & 1u);
    return (us)(r >> 16);
}

// async global->LDS, 16B per lane. LDS dest = wave-uniform base + lane*16.
__device__ __forceinline__ void gld_lds16(const us* g, us* l) {
    __builtin_amdgcn_global_load_lds(
        (const __attribute__((address_space(1))) uint32_t*)(const void*)g,
        (__attribute__((address_space(3))) uint32_t*)(void*)l, 16, 0, 0);
}

// ---------------- transpose + cast: in f32 [K][N] -> out bf16 [N][K] ----------------
__global__ void transpose_k(const float* __restrict__ in,
                            us* __restrict__ out, int K, int N) {
    __shared__ us tile[32][33];
    int nt = blockIdx.x * 32, kt = blockIdx.y * 32;
    int tx = threadIdx.x, ty = threadIdx.y; // (32,8)
    for (int i = 0; i < 4; ++i)
        tile[ty + 8 * i][tx] = f2bf(in[(size_t)(kt + ty + 8 * i) * N + nt + tx]);
    __syncthreads();
    for (int i = 0; i < 4; ++i)
        out[(size_t)(nt + ty + 8 * i) * K + kt + tx] = tile[tx][ty + 8 * i];
}

// ---------------- bf16 transpose: V (strided rows) -> Vt [B*D][T] ----------------
__global__ void vtrans_k(const us* __restrict__ in, us* __restrict__ out, int istride) {
    __shared__ us tile[32][33];
    int b = blockIdx.z;
    int ct = blockIdx.x * 32;   // D tile
    int rt = blockIdx.y * 32;   // T tile
    int tx = threadIdx.x, ty = threadIdx.y; // (32,8)
    for (int i = 0; i < 4; ++i)
        tile[ty + 8 * i][tx] = in[((size_t)b * TSEQ + rt + ty + 8 * i) * istride + ct + tx];
    __syncthreads();
    for (int i = 0; i < 4; ++i)
        out[((size_t)b * DMODEL + ct + ty + 8 * i) * TSEQ + rt + tx] = tile[tx][ty + 8 * i];
}

// ---------------- RMSNorm: f32 in -> bf16 out ----------------
__global__ void rmsnorm_k(const float* __restrict__ x,
                          const float* __restrict__ w,
                          us* __restrict__ out) {
    int row = blockIdx.x, t = threadIdx.x;
    float4 xv = *(const float4*)&x[(size_t)row * DMODEL + t * 4];
    float f[4] = {xv.x, xv.y, xv.z, xv.w};
    float ss = 0.f;
    for (int e = 0; e < 4; ++e) ss += f[e] * f[e];
    for (int m = 1; m < 64; m <<= 1) ss += __shfl_xor(ss, m);
    __shared__ float red[4];
    if ((t & 63) == 0) red[t >> 6] = ss;
    __syncthreads();
    float tot = red[0] + red[1] + red[2] + red[3];
    float sc = rsqrtf(tot * (1.f / DMODEL) + 1e-6f);
    float4 wv = *(const float4*)&w[t * 4];
    float wf[4] = {wv.x, wv.y, wv.z, wv.w};
    us ol[4];
    for (int e = 0; e < 4; ++e) ol[e] = f2bf(f[e] * sc * wf[e]);
    *(uint2*)&out[(size_t)row * DMODEL + t * 4] = *(uint2*)ol;
}

// ---------------- Residual + RMSNorm: out = rmsnorm(a + b [+ b2]) * w ----------------
__global__ void resnorm_k(const us* __restrict__ a, const us* __restrict__ b,
                          const us* __restrict__ b2,
                          const float* __restrict__ w,
                          void* __restrict__ outp, int out_f32) {
    int row = blockIdx.x, t = threadIdx.x;
    us al[4], bl[4], cl[4];
    *(uint2*)al = *(const uint2*)&a[(size_t)row * DMODEL + t * 4];
    *(uint2*)bl = *(const uint2*)&b[(size_t)row * DMODEL + t * 4];
    if (b2) *(uint2*)cl = *(const uint2*)&b2[(size_t)row * DMODEL + t * 4];
    float f[4];
    float ss = 0.f;
    for (int e = 0; e < 4; ++e) {
        f[e] = bf2f(al[e]) + bf2f(bl[e]);
        if (b2) f[e] += bf2f(cl[e]);
        ss += f[e] * f[e];
    }
    for (int m = 1; m < 64; m <<= 1) ss += __shfl_xor(ss, m);
    __shared__ float red[4];
    if ((t & 63) == 0) red[t >> 6] = ss;
    __syncthreads();
    float tot = red[0] + red[1] + red[2] + red[3];
    float sc = rsqrtf(tot * (1.f / DMODEL) + 1e-6f);
    float4 wv = *(const float4*)&w[t * 4];
    float wf[4] = {wv.x, wv.y, wv.z, wv.w};
    if (out_f32) {
        float4 ov;
        ov.x = f[0] * sc * wf[0]; ov.y = f[1] * sc * wf[1];
        ov.z = f[2] * sc * wf[2]; ov.w = f[3] * sc * wf[3];
        *(float4*)&((float*)outp)[(size_t)row * DMODEL + t * 4] = ov;
    } else {
        us ol[4];
        for (int e = 0; e < 4; ++e) ol[e] = f2bf(f[e] * sc * wf[e]);
        *(uint2*)&((us*)outp)[(size_t)row * DMODEL + t * 4] = *(uint2*)ol;
    }
}

// ---------------- GEMM, dbuf LDS, XOR-swizzled tiles, XCD-locality block swizzle ----------
// 1D grid; n -> (x,y,z) such that the GX x-blocks sharing one A-strip have ids that are
// congruent mod 8 -> land on one XCD under round-robin dispatch, so the strip is fetched
// into that XCD's L2 once instead of 8 times (R11: FETCH 135 MB vs 42 MB ideal).
//   c = n & 7 (XCD), b = n >> 3; x = b % GX; g = b / GX; yz = c + 8*g; y = yz & 31, z = yz >> 5.
// LDS bank swizzle validated R10 (conflicts = 0): slot = chunk ^ ((R>>1)&3).
template<int BN, int GX>
__global__ __launch_bounds__(256, (BN == 256) ? 2 : 4)
void gemm_dbuf_k(const us* __restrict__ A,
                 const us* __restrict__ Bt,
                 us* __restrict__ C,
                 int M, int N, int K, int do_silu,
                 int Ks, size_t cstride) {
    constexpr int MI = 4, NI = BN / 32;       // 128->4, 256->8
    constexpr int BDMA = BN / 64;             // B DMAs per wave (16 rows each)
    __shared__ __align__(16) us As[2][128 * 32];
    __shared__ __align__(16) us Bs[2][BN * 32];
    int t = threadIdx.x;
    int n0 = blockIdx.x;
    int c = n0 & 7, bb = n0 >> 3;
    int bx = bb % GX, g = bb / GX;
    int yz = c + 8 * g;
    int by = yz & 31, z = yz >> 5;
    int bm = by * 128, bn = bx * BN;
    int lane = t & 63, wave = t >> 6;
    int wm = (wave & 1) * 64, wn = (wave >> 1) * (BN / 2);
    int lr = lane & 15, lq = lane >> 4;

    int sr = lane >> 2;
    int sc = (((lane & 3) ^ ((lane >> 3) & 3)) * 8);
    const us* gA = A + (size_t)(bm + wave * 32 + sr) * K + sc + (size_t)z * Ks;
    const us* gB = Bt + (size_t)(bn + wave * (BN / 4) + sr) * K + sc + (size_t)z * Ks;
    const int aoff = (wave * 32) * 32;
    const int boff = (wave * (BN / 4)) * 32;
    C += (size_t)z * cstride;

    floatx4 acc[MI][NI];
#pragma unroll
    for (int mi = 0; mi < MI; ++mi)
#pragma unroll
        for (int ni = 0; ni < NI; ++ni)
            acc[mi][ni] = (floatx4){0.f, 0.f, 0.f, 0.f};

#pragma unroll
    for (int i = 0; i < 2; ++i)
        gld_lds16(gA + (size_t)(16 * i) * K, &As[0][aoff + i * 16 * 32]);
#pragma unroll
    for (int i = 0; i < BDMA; ++i)
        gld_lds16(gB + (size_t)(16 * i) * K, &Bs[0][boff + i * 16 * 32]);

    int aslot = ((lq ^ ((lr >> 1) & 3)) << 3);

    int nk = Ks >> 5;
    for (int kk = 0; kk < nk; ++kk) {
        __syncthreads();
        int cur = kk & 1, nxt = cur ^ 1;
        if (kk + 1 < nk) {
            size_t off = (size_t)(kk + 1) * 32;
#pragma unroll
            for (int i = 0; i < 2; ++i)
                gld_lds16(gA + (size_t)(16 * i) * K + off, &As[nxt][aoff + i * 16 * 32]);
#pragma unroll
            for (int i = 0; i < BDMA; ++i)
                gld_lds16(gB + (size_t)(16 * i) * K + off, &Bs[nxt][boff + i * 16 * 32]);
        }
        short8 a[MI], b[NI];
#pragma unroll
        for (int mi = 0; mi < MI; ++mi)
            a[mi] = *(const short8*)&As[cur][(wm + mi * 16 + lr) * 32 + aslot];
#pragma unroll
        for (int ni = 0; ni < NI; ++ni)
            b[ni] = *(const short8*)&Bs[cur][(wn + ni * 16 + lr) * 32 + aslot];
#pragma unroll
        for (int mi = 0; mi < MI; ++mi)
#pragma unroll
            for (int ni = 0; ni < NI; ++ni)
                acc[mi][ni] = __builtin_amdgcn_mfma_f32_16x16x32_bf16(a[mi], b[ni], acc[mi][ni], 0, 0, 0);
    }

#pragma unroll
    for (int mi = 0; mi < MI; ++mi)
#pragma unroll
        for (int ni = 0; ni < NI; ++ni)
#pragma unroll
            for (int r = 0; r < 4; ++r) {
                int m = bm + wm + mi * 16 + lq * 4 + r;
                int nn = bn + wn + ni * 16 + lr;
                float v = acc[mi][ni][r];
                if (do_silu) v = v / (1.f + __expf(-v));
                C[(size_t)m * N + nn] = f2bf(v);
            }
}

// ================= Flash attention: 512-thread blocks, 2 q-tiles sharing one K/V pass ======
// (validated R11: no-max softmax + swizzled DMA staging + paired q-tiles)
#define PSTR 72

template<bool DIAG>
__device__ __forceinline__ void flash_tile_nm(
    const short8& qf0, const short8& qf1,
    floatx4* oa, float* lrw,
    const us* Ks, const us* Vts, us* Ps, const short8& ones,
    int lr, int lq, int sub)
{
    floatx4 s[4];
#pragma unroll
    for (int n = 0; n < 4; ++n) {
        int R = n * 16 + lr;
        short8 kf0 = *(const short8*)&Ks[R * 64 + ((lq ^ (R & 7)) << 3)];
        short8 kf1 = *(const short8*)&Ks[R * 64 + (((lq + 4) ^ (R & 7)) << 3)];
        floatx4 z = (floatx4){0.f, 0.f, 0.f, 0.f};
        z = __builtin_amdgcn_mfma_f32_16x16x32_bf16(qf0, kf0, z, 0, 0, 0);
        s[n] = __builtin_amdgcn_mfma_f32_16x16x32_bf16(qf1, kf1, z, 0, 0, 0);
    }
    if (DIAG) {
#pragma unroll
        for (int n = 0; n < 4; ++n)
#pragma unroll
            for (int r = 0; r < 4; ++r)
                if ((n * 16 + lr) > (sub * 16 + lq * 4 + r)) s[n][r] = -1e30f;  // exp2 -> 0
    }
#pragma unroll
    for (int n = 0; n < 4; ++n)
#pragma unroll
        for (int r = 0; r < 4; ++r)
            Ps[(lq * 4 + r) * PSTR + n * 16 + lr] = f2bf(__builtin_amdgcn_exp2f(s[n][r]));

    floatx4 zs = (floatx4){0.f, 0.f, 0.f, 0.f};
#pragma unroll
    for (int kx = 0; kx < 2; ++kx) {
        short8 pf = *(const short8*)&Ps[lr * PSTR + kx * 32 + lq * 8];
        zs = __builtin_amdgcn_mfma_f32_16x16x32_bf16(pf, ones, zs, 0, 0, 0);
#pragma unroll
        for (int nd = 0; nd < 4; ++nd) {
            int R = nd * 16 + lr;
            short8 vf = *(const short8*)&Vts[R * 64 + ((((kx << 2) | lq) ^ (R & 7)) << 3)];
            oa[nd] = __builtin_amdgcn_mfma_f32_16x16x32_bf16(pf, vf, oa[nd], 0, 0, 0);
        }
    }
#pragma unroll
    for (int r = 0; r < 4; ++r) lrw[r] += zs[r];
}

// grid (24, B*H), 512 threads. j<16: P=j, part0: kt 0..min(2P+1,15), fin iff P<8.
// j>=16: P=j-8, part1: kt 16..2P+1. Waves 0-3 -> qtA=2P; waves 4-7 -> qtB=2P+1.
__global__ __launch_bounds__(512, 6) void attn_k(const us* __restrict__ q,
                                                 const us* __restrict__ kg,
                                                 const us* __restrict__ vt,
                                                 us* __restrict__ o,
                                                 us* __restrict__ Po,
                                                 float* __restrict__ Pl) {
    __shared__ __align__(16) us Ks[2][64 * 64];
    __shared__ __align__(16) us Vts[2][64 * 64];
    __shared__ __align__(16) us Ps[8 * 16 * PSTR];
    int j = blockIdx.x;
    int part = (j >= 16);
    int P = part ? (j - 8) : j;
    int qtA = 2 * P, qtB = 2 * P + 1;
    int k0 = part ? 16 : 0;
    int k1 = part ? qtB : (qtB < 15 ? qtB : 15);
    bool fin = (!part) && (P < 8);
    int bh = blockIdx.y;
    int b = bh >> 4, h = bh & 15;
    size_t base = (size_t)b * TSEQ;
    const us* vth = vt + ((size_t)b * DMODEL + h * 64) * TSEQ;
    int t = threadIdx.x, lane = t & 63, wave = t >> 6;   // wave 0..7
    int sub = wave & 3, grp = wave >> 2;                 // strip index, q-tile group
    int myqt = grp ? qtB : qtA;
    int lr = lane & 15, lq = lane >> 4;

    const float SC = 0.18033688011112042f;  // (1/8)*log2(e)
    int qrow = myqt * 64 + sub * 16 + lr;
    short8 qf0 = *(const short8*)&q[(base + qrow) * QKVS + h * 64 + lq * 8];
    short8 qf1 = *(const short8*)&q[(base + qrow) * QKVS + h * 64 + 32 + lq * 8];
#pragma unroll
    for (int e = 0; e < 8; ++e) {
        qf0[e] = (short)f2bf(bf2f((us)qf0[e]) * SC);
        qf1[e] = (short)f2bf(bf2f((us)qf1[e]) * SC);
    }
    short8 ones;
#pragma unroll
    for (int e = 0; e < 8; ++e) ones[e] = (short)0x3F80;  // bf16 1.0

    us* Psw = &Ps[wave * 16 * PSTR];

    floatx4 oa[4];
    float lrw[4] = {0.f, 0.f, 0.f, 0.f};
#pragma unroll
    for (int i = 0; i < 4; ++i) oa[i] = (floatx4){0.f, 0.f, 0.f, 0.f};

    // staging: 8 waves x (1 K-DMA + 1 V-DMA), each DMA = 8 rows x 8 swizzled chunks
    int rsub = lane >> 3;
    int cda = ((lane & 7) ^ rsub) * 8;
    const us* gK = kg + (base + wave * 8 + rsub) * QKVS + h * 64 + cda;
    const us* gV = vth + (size_t)(wave * 8 + rsub) * TSEQ + cda;

    gld_lds16(gK + (size_t)(k0 * 64) * QKVS, &Ks[0][(wave * 8) * 64]);
    gld_lds16(gV + k0 * 64, &Vts[0][(wave * 8) * 64]);

    for (int kt = k0; kt <= k1; ++kt) {
        __syncthreads();   // buf[cur] staged (vmcnt drained), readers of buf[nxt] done
        int cur = (kt - k0) & 1, nxt = cur ^ 1;
        if (kt < k1) {
            gld_lds16(gK + (size_t)((kt + 1) * 64) * QKVS, &Ks[nxt][(wave * 8) * 64]);
            gld_lds16(gV + (kt + 1) * 64, &Vts[nxt][(wave * 8) * 64]);
        }
        if (kt <= myqt) {
            if (kt == myqt)
                flash_tile_nm<true>(qf0, qf1, oa, lrw, Ks[cur], Vts[cur], Psw, ones, lr, lq, sub);
            else
                flash_tile_nm<false>(qf0, qf1, oa, lrw, Ks[cur], Vts[cur], Psw, ones, lr, lq, sub);
        }
    }

    if (fin) {
#pragma unroll
        for (int nd = 0; nd < 4; ++nd)
#pragma unroll
            for (int r = 0; r < 4; ++r) {
                int tok = myqt * 64 + sub * 16 + lq * 4 + r;
                o[(base + tok) * DMODEL + h * 64 + nd * 16 + lr] = f2bf(oa[nd][r] / lrw[r]);
            }
    } else {
#pragma unroll
        for (int nd = 0; nd < 4; ++nd)
#pragma unroll
            for (int r = 0; r < 4; ++r) {
                int tok = myqt * 64 + sub * 16 + lq * 4 + r;
                size_t pb = ((size_t)(part * BATCH + b) * 1024 + (tok - 1024)) * 1024;
                Po[pb + h * 64 + nd * 16 + lr] = f2bf(oa[nd][r]);
            }
        if (lr == 0) {
#pragma unroll
            for (int r = 0; r < 4; ++r) {
                int tok = myqt * 64 + sub * 16 + lq * 4 + r;
                Pl[((part * BATCH + b) * NHEADS + h) * TSEQ + tok] = lrw[r];
            }
        }
    }
}

// merge the two partials for rows t in [1024, 2048): O = (O0+O1)/(l0+l1)
__global__ void merge_k(const us* __restrict__ Po, const float* __restrict__ Pl,
                        us* __restrict__ ab) {
    int row = blockIdx.x;            // 0..2047
    int b = row >> 10, tloc = row & 1023;
    int t = 1024 + tloc;
    int t4 = threadIdx.x * 4;
    int h = t4 >> 6;
    float l0 = Pl[((0 * BATCH + b) * NHEADS + h) * TSEQ + t];
    float l1 = Pl[((1 * BATCH + b) * NHEADS + h) * TSEQ + t];
    float inv = 1.f / (l0 + l1);
    size_t o0 = ((size_t)(0 * BATCH + b) * 1024 + tloc) * 1024 + t4;
    size_t o1 = ((size_t)(1 * BATCH + b) * 1024 + tloc) * 1024 + t4;
    us p0[4], p1[4], ol[4];
    *(uint2*)p0 = *(const uint2*)&Po[o0];
    *(uint2*)p1 = *(const uint2*)&Po[o1];
    for (int e = 0; e < 4; ++e)
        ol[e] = f2bf((bf2f(p0[e]) + bf2f(p1[e])) * inv);
    *(uint2*)&ab[((size_t)b * TSEQ + t) * DMODEL + t4] = *(uint2*)ol;
}

// ---------------- launch ----------------
extern "C" void kernel_launch(void* const* d_in, const int* in_sizes, int n_in,
                              void* d_out, int out_size, void* d_ws, size_t ws_size,
                              hipStream_t stream) {
    const float* x      = (const float*)d_in[0];
    const float* w_pre  = (const float*)d_in[1];
    const float* wq     = (const float*)d_in[2];
    const float* wk     = (const float*)d_in[3];
    const float* wv     = (const float*)d_in[4];
    const float* wo     = (const float*)d_in[5];
    const float* w_attn = (const float*)d_in[6];
    const float* w1     = (const float*)d_in[7];
    const float* w2     = (const float*)d_in[8];
    const float* w_ffn  = (const float*)d_in[9];

    char* ws = (char*)d_ws;
    const size_t MB = 1024 * 1024;
    us* hb    = (us*)(ws + 0);        // 8 MB residual h; dead after resnorm_attn
    us* qkvb  = (us*)(ws + 8 * MB);   // 24 MB fused q|k|v
    us* ab    = (us*)(ws + 32 * MB);  // 8 MB attn merged out
    us* vtb   = (us*)(ws + 40 * MB);  // 8 MB V^T; dead after attn
    us* ob0   = (us*)(ws + 40 * MB);  // o-proj partial 0 (aliases vtb, after attn)
    us* ob1   = (us*)(ws + 48 * MB);  // o-proj partial 1 (aliases Pob, after merge)
    us* Pob   = (us*)(ws + 48 * MB);  // 8 MB attn partials; dead after merge
    us* yb    = (us*)(ws + 48 * MB);  // y, written in-place over ob1 by resnorm (elementwise-safe)
    us* wqkvt = (us*)(ws + 56 * MB);  // 6 MB
    us* wot   = (us*)(ws + 62 * MB);  // 2 MB
    us* w1t   = (us*)(ws + 64 * MB);  // 8 MB
    us* w2t   = (us*)(ws + 72 * MB);  // 8 MB
    float* Pl = (float*)(ws + 80 * MB); // 1 MB l partial stats
    us* midb  = (us*)(ws + 8 * MB);   // 32 MB FFN mid (qkvb+ab dead)
    us* fb0   = (us*)(ws + 0);        // FFN2 partial 0 (hb dead)
    us* fb1   = (us*)(ws + 40 * MB);  // FFN2 partial 1 (ob0 dead after resnorm_attn)
    const size_t FB1_OFF = (40 * MB) / 2; // elements from fb0 to fb1

    dim3 tb(32, 8);
    transpose_k<<<dim3(32, 32), tb, 0, stream>>>(wq, wqkvt, DMODEL, DMODEL);
    transpose_k<<<dim3(32, 32), tb, 0, stream>>>(wk, wqkvt + 1024 * 1024, DMODEL, DMODEL);
    transpose_k<<<dim3(32, 32), tb, 0, stream>>>(wv, wqkvt + 2 * 1024 * 1024, DMODEL, DMODEL);
    transpose_k<<<dim3(32, 32), tb, 0, stream>>>(wo, wot, DMODEL, DMODEL);
    transpose_k<<<dim3(FFDIM / 32, 32), tb, 0, stream>>>(w1, w1t, DMODEL, FFDIM);
    transpose_k<<<dim3(32, FFDIM / 32), tb, 0, stream>>>(w2, w2t, FFDIM, DMODEL);

    rmsnorm_k<<<BT, 256, 0, stream>>>(x, w_pre, hb);

    // fused QKV: GX=24, 768 blocks (XCD-swizzled 1D grid)
    gemm_dbuf_k<128, 24><<<dim3(768), 256, 0, stream>>>(
        hb, wqkvt, qkvb, BT, QKVS, DMODEL, 0, DMODEL, 0);

    vtrans_k<<<dim3(DMODEL / 32, TSEQ / 32, BATCH), tb, 0, stream>>>(qkvb + 2048, vtb, QKVS);

    attn_k<<<dim3(24, BATCH * NHEADS), 512, 0, stream>>>(qkvb, qkvb + 1024, vtb, ab, Pob, Pl);
    merge_k<<<dim3(BATCH * 1024), 256, 0, stream>>>(Pob, Pl, ab);

    // O-proj: GX=8, split-K=2 -> 512 blocks
    gemm_dbuf_k<128, 8><<<dim3(512), 256, 0, stream>>>(
        ab, wot, ob0, BT, DMODEL, DMODEL, 0, DMODEL / 2, (size_t)BT * DMODEL);
    resnorm_k<<<BT, 256, 0, stream>>>(hb, ob0, ob1, w_attn, yb, 0);

    // FFN1: BN=256, GX=16, 512 blocks
    gemm_dbuf_k<256, 16><<<dim3(512), 256, 0, stream>>>(
        yb, w1t, midb, BT, FFDIM, DMODEL, 1, DMODEL, 0);
    // FFN2: GX=8, split-K=2 -> 512 blocks
    gemm_dbuf_k<128, 8><<<dim3(512), 256, 0, stream>>>(
        midb, w2t, fb0, BT, DMODEL, FFDIM, 0, FFDIM / 2, FB1_OFF);
    resnorm_k<<<BT, 256, 0, stream>>>(yb, fb0, fb1, w_ffn, d_out, 1);
}

// Round 13
// 334.267 us; speedup vs baseline: 1.0381x; 1.0381x over previous
//
#include <hip/hip_runtime.h>
#include <cstdint>
#include <cstddef>

#define TSEQ   2048
#define BATCH  2
#define BT     4096      // BATCH*TSEQ
#define DMODEL 1024
#define NHEADS 16
#define HDIM   64
#define FFDIM  4096
#define QKVS   3072      // row stride of fused qkv buffer

typedef __attribute__((ext_vector_type(8))) short short8;    // 8 bf16 = 4 VGPRs
typedef __attribute__((ext_vector_type(4))) float floatx4;   // MFMA acc
typedef unsigned short us;

__device__ __forceinline__ float bf2f(us u) {
    union { unsigned int i; float f; } v; v.i = ((unsigned int)u) << 16; return v.f;
}
__device__ __forceinline__ us f2bf(float f) {
    union { float f; unsigned int i; } v; v.f = f;
    unsigned int r = v.i + 0x7fffu + ((v.i >> 16) & 1u);
    return (us)(r >> 16);
}

// async global->LDS, 16B per lane. LDS dest = wave-uniform base + lane*16.
__device__ __forceinline__ void gld_lds16(const us* g, us* l) {
    __builtin_amdgcn_global_load_lds(
        (const __attribute__((address_space(1))) uint32_t*)(const void*)g,
        (__attribute__((address_space(3))) uint32_t*)(void*)l, 16, 0, 0);
}

// ---------------- transpose + cast: in f32 [K][N] -> out bf16 [N][K] ----------------
__global__ void transpose_k(const float* __restrict__ in,
                            us* __restrict__ out, int K, int N) {
    __shared__ us tile[32][33];
    int nt = blockIdx.x * 32, kt = blockIdx.y * 32;
    int tx = threadIdx.x, ty = threadIdx.y; // (32,8)
    for (int i = 0; i < 4; ++i)
        tile[ty + 8 * i][tx] = f2bf(in[(size_t)(kt + ty + 8 * i) * N + nt + tx]);
    __syncthreads();
    for (int i = 0; i < 4; ++i)
        out[(size_t)(nt + ty + 8 * i) * K + kt + tx] = tile[tx][ty + 8 * i];
}

// ---------------- bf16 transpose: V (strided rows) -> Vt [B*D][T] ----------------
__global__ void vtrans_k(const us* __restrict__ in, us* __restrict__ out, int istride) {
    __shared__ us tile[32][33];
    int b = blockIdx.z;
    int ct = blockIdx.x * 32;   // D tile
    int rt = blockIdx.y * 32;   // T tile
    int tx = threadIdx.x, ty = threadIdx.y; // (32,8)
    for (int i = 0; i < 4; ++i)
        tile[ty + 8 * i][tx] = in[((size_t)b * TSEQ + rt + ty + 8 * i) * istride + ct + tx];
    __syncthreads();
    for (int i = 0; i < 4; ++i)
        out[((size_t)b * DMODEL + ct + ty + 8 * i) * TSEQ + rt + tx] = tile[tx][ty + 8 * i];
}

// ---------------- RMSNorm: f32 in -> bf16 out ----------------
__global__ void rmsnorm_k(const float* __restrict__ x,
                          const float* __restrict__ w,
                          us* __restrict__ out) {
    int row = blockIdx.x, t = threadIdx.x;
    float4 xv = *(const float4*)&x[(size_t)row * DMODEL + t * 4];
    float f[4] = {xv.x, xv.y, xv.z, xv.w};
    float ss = 0.f;
    for (int e = 0; e < 4; ++e) ss += f[e] * f[e];
    for (int m = 1; m < 64; m <<= 1) ss += __shfl_xor(ss, m);
    __shared__ float red[4];
    if ((t & 63) == 0) red[t >> 6] = ss;
    __syncthreads();
    float tot = red[0] + red[1] + red[2] + red[3];
    float sc = rsqrtf(tot * (1.f / DMODEL) + 1e-6f);
    float4 wv = *(const float4*)&w[t * 4];
    float wf[4] = {wv.x, wv.y, wv.z, wv.w};
    us ol[4];
    for (int e = 0; e < 4; ++e) ol[e] = f2bf(f[e] * sc * wf[e]);
    *(uint2*)&out[(size_t)row * DMODEL + t * 4] = *(uint2*)ol;
}

// ---------------- Residual + RMSNorm: out = rmsnorm(a + b [+ b2]) * w ----------------
__global__ void resnorm_k(const us* __restrict__ a, const us* __restrict__ b,
                          const us* __restrict__ b2,
                          const float* __restrict__ w,
                          void* __restrict__ outp, int out_f32) {
    int row = blockIdx.x, t = threadIdx.x;
    us al[4], bl[4], cl[4];
    *(uint2*)al = *(const uint2*)&a[(size_t)row * DMODEL + t * 4];
    *(uint2*)bl = *(const uint2*)&b[(size_t)row * DMODEL + t * 4];
    if (b2) *(uint2*)cl = *(const uint2*)&b2[(size_t)row * DMODEL + t * 4];
    float f[4];
    float ss = 0.f;
    for (int e = 0; e < 4; ++e) {
        f[e] = bf2f(al[e]) + bf2f(bl[e]);
        if (b2) f[e] += bf2f(cl[e]);
        ss += f[e] * f[e];
    }
    for (int m = 1; m < 64; m <<= 1) ss += __shfl_xor(ss, m);
    __shared__ float red[4];
    if ((t & 63) == 0) red[t >> 6] = ss;
    __syncthreads();
    float tot = red[0] + red[1] + red[2] + red[3];
    float sc = rsqrtf(tot * (1.f / DMODEL) + 1e-6f);
    float4 wv = *(const float4*)&w[t * 4];
    float wf[4] = {wv.x, wv.y, wv.z, wv.w};
    if (out_f32) {
        float4 ov;
        ov.x = f[0] * sc * wf[0]; ov.y = f[1] * sc * wf[1];
        ov.z = f[2] * sc * wf[2]; ov.w = f[3] * sc * wf[3];
        *(float4*)&((float*)outp)[(size_t)row * DMODEL + t * 4] = ov;
    } else {
        us ol[4];
        for (int e = 0; e < 4; ++e) ol[e] = f2bf(f[e] * sc * wf[e]);
        *(uint2*)&((us*)outp)[(size_t)row * DMODEL + t * 4] = *(uint2*)ol;
    }
}

// ---------------- GEMM, dbuf LDS, XOR-swizzled tiles, optional XCD block swizzle ----------
// SWZ=true: n -> (x,y,z) with the GX x-blocks sharing an A-strip congruent mod 8 -> one XCD
//   (R12: wins when per-XCD working set fits 4 MB L2 — QKV/O-proj/FFN2; loses for FFN1
//    where B=8 MB per XCD thrashes L2, so FFN1 uses SWZ=false = R11 row-major decode).
// LDS bank swizzle validated R10 (conflicts = 0): slot = chunk ^ ((R>>1)&3).
template<int BN, int GX, bool SWZ>
__global__ __launch_bounds__(256, (BN == 256) ? 2 : 4)
void gemm_dbuf_k(const us* __restrict__ A,
                 const us* __restrict__ Bt,
                 us* __restrict__ C,
                 int M, int N, int K, int do_silu,
                 int Ks, size_t cstride) {
    constexpr int MI = 4, NI = BN / 32;       // 128->4, 256->8
    constexpr int BDMA = BN / 64;             // B DMAs per wave (16 rows each)
    __shared__ __align__(16) us As[2][128 * 32];
    __shared__ __align__(16) us Bs[2][BN * 32];
    int t = threadIdx.x;
    int n0 = blockIdx.x;
    int bx, by, z;
    if (SWZ) {
        int c = n0 & 7, bb = n0 >> 3;
        bx = bb % GX;
        int g = bb / GX;
        int yz = c + 8 * g;
        by = yz & 31; z = yz >> 5;
    } else {
        bx = n0 % GX;
        int bb = n0 / GX;
        by = bb & 31; z = bb >> 5;
    }
    int bm = by * 128, bn = bx * BN;
    int lane = t & 63, wave = t >> 6;
    int wm = (wave & 1) * 64, wn = (wave >> 1) * (BN / 2);
    int lr = lane & 15, lq = lane >> 4;

    int sr = lane >> 2;
    int sc = (((lane & 3) ^ ((lane >> 3) & 3)) * 8);
    const us* gA = A + (size_t)(bm + wave * 32 + sr) * K + sc + (size_t)z * Ks;
    const us* gB = Bt + (size_t)(bn + wave * (BN / 4) + sr) * K + sc + (size_t)z * Ks;
    const int aoff = (wave * 32) * 32;
    const int boff = (wave * (BN / 4)) * 32;
    C += (size_t)z * cstride;

    floatx4 acc[MI][NI];
#pragma unroll
    for (int mi = 0; mi < MI; ++mi)
#pragma unroll
        for (int ni = 0; ni < NI; ++ni)
            acc[mi][ni] = (floatx4){0.f, 0.f, 0.f, 0.f};

#pragma unroll
    for (int i = 0; i < 2; ++i)
        gld_lds16(gA + (size_t)(16 * i) * K, &As[0][aoff + i * 16 * 32]);
#pragma unroll
    for (int i = 0; i < BDMA; ++i)
        gld_lds16(gB + (size_t)(16 * i) * K, &Bs[0][boff + i * 16 * 32]);

    int aslot = ((lq ^ ((lr >> 1) & 3)) << 3);

    int nk = Ks >> 5;
    for (int kk = 0; kk < nk; ++kk) {
        __syncthreads();
        int cur = kk & 1, nxt = cur ^ 1;
        if (kk + 1 < nk) {
            size_t off = (size_t)(kk + 1) * 32;
#pragma unroll
            for (int i = 0; i < 2; ++i)
                gld_lds16(gA + (size_t)(16 * i) * K + off, &As[nxt][aoff + i * 16 * 32]);
#pragma unroll
            for (int i = 0; i < BDMA; ++i)
                gld_lds16(gB + (size_t)(16 * i) * K + off, &Bs[nxt][boff + i * 16 * 32]);
        }
        short8 a[MI], b[NI];
#pragma unroll
        for (int mi = 0; mi < MI; ++mi)
            a[mi] = *(const short8*)&As[cur][(wm + mi * 16 + lr) * 32 + aslot];
#pragma unroll
        for (int ni = 0; ni < NI; ++ni)
            b[ni] = *(const short8*)&Bs[cur][(wn + ni * 16 + lr) * 32 + aslot];
#pragma unroll
        for (int mi = 0; mi < MI; ++mi)
#pragma unroll
            for (int ni = 0; ni < NI; ++ni)
                acc[mi][ni] = __builtin_amdgcn_mfma_f32_16x16x32_bf16(a[mi], b[ni], acc[mi][ni], 0, 0, 0);
    }

#pragma unroll
    for (int mi = 0; mi < MI; ++mi)
#pragma unroll
        for (int ni = 0; ni < NI; ++ni)
#pragma unroll
            for (int r = 0; r < 4; ++r) {
                int m = bm + wm + mi * 16 + lq * 4 + r;
                int nn = bn + wn + ni * 16 + lr;
                float v = acc[mi][ni][r];
                if (do_silu) v = v / (1.f + __expf(-v));
                C[(size_t)m * N + nn] = f2bf(v);
            }
}

// ================= Flash attention: 512-thread blocks, 2 q-tiles sharing one K/V pass ======
// (validated R11: no-max softmax + swizzled DMA staging + paired q-tiles)
#define PSTR 72

template<bool DIAG>
__device__ __forceinline__ void flash_tile_nm(
    const short8& qf0, const short8& qf1,
    floatx4* oa, float* lrw,
    const us* Ks, const us* Vts, us* Ps, const short8& ones,
    int lr, int lq, int sub)
{
    floatx4 s[4];
#pragma unroll
    for (int n = 0; n < 4; ++n) {
        int R = n * 16 + lr;
        short8 kf0 = *(const short8*)&Ks[R * 64 + ((lq ^ (R & 7)) << 3)];
        short8 kf1 = *(const short8*)&Ks[R * 64 + (((lq + 4) ^ (R & 7)) << 3)];
        floatx4 z = (floatx4){0.f, 0.f, 0.f, 0.f};
        z = __builtin_amdgcn_mfma_f32_16x16x32_bf16(qf0, kf0, z, 0, 0, 0);
        s[n] = __builtin_amdgcn_mfma_f32_16x16x32_bf16(qf1, kf1, z, 0, 0, 0);
    }
    if (DIAG) {
#pragma unroll
        for (int n = 0; n < 4; ++n)
#pragma unroll
            for (int r = 0; r < 4; ++r)
                if ((n * 16 + lr) > (sub * 16 + lq * 4 + r)) s[n][r] = -1e30f;  // exp2 -> 0
    }
#pragma unroll
    for (int n = 0; n < 4; ++n)
#pragma unroll
        for (int r = 0; r < 4; ++r)
            Ps[(lq * 4 + r) * PSTR + n * 16 + lr] = f2bf(__builtin_amdgcn_exp2f(s[n][r]));

    floatx4 zs = (floatx4){0.f, 0.f, 0.f, 0.f};
#pragma unroll
    for (int kx = 0; kx < 2; ++kx) {
        short8 pf = *(const short8*)&Ps[lr * PSTR + kx * 32 + lq * 8];
        zs = __builtin_amdgcn_mfma_f32_16x16x32_bf16(pf, ones, zs, 0, 0, 0);
#pragma unroll
        for (int nd = 0; nd < 4; ++nd) {
            int R = nd * 16 + lr;
            short8 vf = *(const short8*)&Vts[R * 64 + ((((kx << 2) | lq) ^ (R & 7)) << 3)];
            oa[nd] = __builtin_amdgcn_mfma_f32_16x16x32_bf16(pf, vf, oa[nd], 0, 0, 0);
        }
    }
#pragma unroll
    for (int r = 0; r < 4; ++r) lrw[r] += zs[r];
}

// grid (24, B*H), 512 threads. j<16: P=j, part0: kt 0..min(2P+1,15), fin iff P<8.
// j>=16: P=j-8, part1: kt 16..2P+1. Waves 0-3 -> qtA=2P; waves 4-7 -> qtB=2P+1.
__global__ __launch_bounds__(512, 6) void attn_k(const us* __restrict__ q,
                                                 const us* __restrict__ kg,
                                                 const us* __restrict__ vt,
                                                 us* __restrict__ o,
                                                 us* __restrict__ Po,
                                                 float* __restrict__ Pl) {
    __shared__ __align__(16) us Ks[2][64 * 64];
    __shared__ __align__(16) us Vts[2][64 * 64];
    __shared__ __align__(16) us Ps[8 * 16 * PSTR];
    int j = blockIdx.x;
    int part = (j >= 16);
    int P = part ? (j - 8) : j;
    int qtA = 2 * P, qtB = 2 * P + 1;
    int k0 = part ? 16 : 0;
    int k1 = part ? qtB : (qtB < 15 ? qtB : 15);
    bool fin = (!part) && (P < 8);
    int bh = blockIdx.y;
    int b = bh >> 4, h = bh & 15;
    size_t base = (size_t)b * TSEQ;
    const us* vth = vt + ((size_t)b * DMODEL + h * 64) * TSEQ;
    int t = threadIdx.x, lane = t & 63, wave = t >> 6;   // wave 0..7
    int sub = wave & 3, grp = wave >> 2;                 // strip index, q-tile group
    int myqt = grp ? qtB : qtA;
    int lr = lane & 15, lq = lane >> 4;

    const float SC = 0.18033688011112042f;  // (1/8)*log2(e)
    int qrow = myqt * 64 + sub * 16 + lr;
    short8 qf0 = *(const short8*)&q[(base + qrow) * QKVS + h * 64 + lq * 8];
    short8 qf1 = *(const short8*)&q[(base + qrow) * QKVS + h * 64 + 32 + lq * 8];
#pragma unroll
    for (int e = 0; e < 8; ++e) {
        qf0[e] = (short)f2bf(bf2f((us)qf0[e]) * SC);
        qf1[e] = (short)f2bf(bf2f((us)qf1[e]) * SC);
    }
    short8 ones;
#pragma unroll
    for (int e = 0; e < 8; ++e) ones[e] = (short)0x3F80;  // bf16 1.0

    us* Psw = &Ps[wave * 16 * PSTR];

    floatx4 oa[4];
    float lrw[4] = {0.f, 0.f, 0.f, 0.f};
#pragma unroll
    for (int i = 0; i < 4; ++i) oa[i] = (floatx4){0.f, 0.f, 0.f, 0.f};

    // staging: 8 waves x (1 K-DMA + 1 V-DMA), each DMA = 8 rows x 8 swizzled chunks
    int rsub = lane >> 3;
    int cda = ((lane & 7) ^ rsub) * 8;
    const us* gK = kg + (base + wave * 8 + rsub) * QKVS + h * 64 + cda;
    const us* gV = vth + (size_t)(wave * 8 + rsub) * TSEQ + cda;

    gld_lds16(gK + (size_t)(k0 * 64) * QKVS, &Ks[0][(wave * 8) * 64]);
    gld_lds16(gV + k0 * 64, &Vts[0][(wave * 8) * 64]);

    for (int kt = k0; kt <= k1; ++kt) {
        __syncthreads();   // buf[cur] staged (vmcnt drained), readers of buf[nxt] done
        int cur = (kt - k0) & 1, nxt = cur ^ 1;
        if (kt < k1) {
            gld_lds16(gK + (size_t)((kt + 1) * 64) * QKVS, &Ks[nxt][(wave * 8) * 64]);
            gld_lds16(gV + (kt + 1) * 64, &Vts[nxt][(wave * 8) * 64]);
        }
        if (kt <= myqt) {
            if (kt == myqt)
                flash_tile_nm<true>(qf0, qf1, oa, lrw, Ks[cur], Vts[cur], Psw, ones, lr, lq, sub);
            else
                flash_tile_nm<false>(qf0, qf1, oa, lrw, Ks[cur], Vts[cur], Psw, ones, lr, lq, sub);
        }
    }

    if (fin) {
#pragma unroll
        for (int nd = 0; nd < 4; ++nd)
#pragma unroll
            for (int r = 0; r < 4; ++r) {
                int tok = myqt * 64 + sub * 16 + lq * 4 + r;
                o[(base + tok) * DMODEL + h * 64 + nd * 16 + lr] = f2bf(oa[nd][r] / lrw[r]);
            }
    } else {
#pragma unroll
        for (int nd = 0; nd < 4; ++nd)
#pragma unroll
            for (int r = 0; r < 4; ++r) {
                int tok = myqt * 64 + sub * 16 + lq * 4 + r;
                size_t pb = ((size_t)(part * BATCH + b) * 1024 + (tok - 1024)) * 1024;
                Po[pb + h * 64 + nd * 16 + lr] = f2bf(oa[nd][r]);
            }
        if (lr == 0) {
#pragma unroll
            for (int r = 0; r < 4; ++r) {
                int tok = myqt * 64 + sub * 16 + lq * 4 + r;
                Pl[((part * BATCH + b) * NHEADS + h) * TSEQ + tok] = lrw[r];
            }
        }
    }
}

// merge the two partials for rows t in [1024, 2048): O = (O0+O1)/(l0+l1)
__global__ void merge_k(const us* __restrict__ Po, const float* __restrict__ Pl,
                        us* __restrict__ ab) {
    int row = blockIdx.x;            // 0..2047
    int b = row >> 10, tloc = row & 1023;
    int t = 1024 + tloc;
    int t4 = threadIdx.x * 4;
    int h = t4 >> 6;
    float l0 = Pl[((0 * BATCH + b) * NHEADS + h) * TSEQ + t];
    float l1 = Pl[((1 * BATCH + b) * NHEADS + h) * TSEQ + t];
    float inv = 1.f / (l0 + l1);
    size_t o0 = ((size_t)(0 * BATCH + b) * 1024 + tloc) * 1024 + t4;
    size_t o1 = ((size_t)(1 * BATCH + b) * 1024 + tloc) * 1024 + t4;
    us p0[4], p1[4], ol[4];
    *(uint2*)p0 = *(const uint2*)&Po[o0];
    *(uint2*)p1 = *(const uint2*)&Po[o1];
    for (int e = 0; e < 4; ++e)
        ol[e] = f2bf((bf2f(p0[e]) + bf2f(p1[e])) * inv);
    *(uint2*)&ab[((size_t)b * TSEQ + t) * DMODEL + t4] = *(uint2*)ol;
}

// ---------------- launch ----------------
extern "C" void kernel_launch(void* const* d_in, const int* in_sizes, int n_in,
                              void* d_out, int out_size, void* d_ws, size_t ws_size,
                              hipStream_t stream) {
    const float* x      = (const float*)d_in[0];
    const float* w_pre  = (const float*)d_in[1];
    const float* wq     = (const float*)d_in[2];
    const float* wk     = (const float*)d_in[3];
    const float* wv     = (const float*)d_in[4];
    const float* wo     = (const float*)d_in[5];
    const float* w_attn = (const float*)d_in[6];
    const float* w1     = (const float*)d_in[7];
    const float* w2     = (const float*)d_in[8];
    const float* w_ffn  = (const float*)d_in[9];

    char* ws = (char*)d_ws;
    const size_t MB = 1024 * 1024;
    us* hb    = (us*)(ws + 0);        // 8 MB residual h; dead after resnorm_attn
    us* qkvb  = (us*)(ws + 8 * MB);   // 24 MB fused q|k|v
    us* ab    = (us*)(ws + 32 * MB);  // 8 MB attn merged out
    us* vtb   = (us*)(ws + 40 * MB);  // 8 MB V^T; dead after attn
    us* ob0   = (us*)(ws + 40 * MB);  // o-proj partial 0 (aliases vtb, after attn)
    us* ob1   = (us*)(ws + 48 * MB);  // o-proj partial 1 (aliases Pob, after merge)
    us* Pob   = (us*)(ws + 48 * MB);  // 8 MB attn partials; dead after merge
    us* yb    = (us*)(ws + 48 * MB);  // y, written in-place over ob1 by resnorm (elementwise-safe)
    us* wqkvt = (us*)(ws + 56 * MB);  // 6 MB
    us* wot   = (us*)(ws + 62 * MB);  // 2 MB
    us* w1t   = (us*)(ws + 64 * MB);  // 8 MB
    us* w2t   = (us*)(ws + 72 * MB);  // 8 MB
    float* Pl = (float*)(ws + 80 * MB); // 1 MB l partial stats
    us* midb  = (us*)(ws + 8 * MB);   // 32 MB FFN mid (qkvb+ab dead)
    us* fb0   = (us*)(ws + 0);        // FFN2 partial 0 (hb dead)
    us* fb1   = (us*)(ws + 40 * MB);  // FFN2 partial 1 (ob0 dead after resnorm_attn)
    const size_t FB1_OFF = (40 * MB) / 2; // elements from fb0 to fb1

    dim3 tb(32, 8);
    transpose_k<<<dim3(32, 32), tb, 0, stream>>>(wq, wqkvt, DMODEL, DMODEL);
    transpose_k<<<dim3(32, 32), tb, 0, stream>>>(wk, wqkvt + 1024 * 1024, DMODEL, DMODEL);
    transpose_k<<<dim3(32, 32), tb, 0, stream>>>(wv, wqkvt + 2 * 1024 * 1024, DMODEL, DMODEL);
    transpose_k<<<dim3(32, 32), tb, 0, stream>>>(wo, wot, DMODEL, DMODEL);
    transpose_k<<<dim3(FFDIM / 32, 32), tb, 0, stream>>>(w1, w1t, DMODEL, FFDIM);
    transpose_k<<<dim3(32, FFDIM / 32), tb, 0, stream>>>(w2, w2t, FFDIM, DMODEL);

    rmsnorm_k<<<BT, 256, 0, stream>>>(x, w_pre, hb);

    // fused QKV: GX=24, 768 blocks, XCD-swizzled (R12: improved)
    gemm_dbuf_k<128, 24, true><<<dim3(768), 256, 0, stream>>>(
        hb, wqkvt, qkvb, BT, QKVS, DMODEL, 0, DMODEL, 0);

    vtrans_k<<<dim3(DMODEL / 32, TSEQ / 32, BATCH), tb, 0, stream>>>(qkvb + 2048, vtb, QKVS);

    attn_k<<<dim3(24, BATCH * NHEADS), 512, 0, stream>>>(qkvb, qkvb + 1024, vtb, ab, Pob, Pl);
    merge_k<<<dim3(BATCH * 1024), 256, 0, stream>>>(Pob, Pl, ab);

    // O-proj: GX=8, split-K=2 -> 512 blocks, XCD-swizzled (R12: improved)
    gemm_dbuf_k<128, 8, true><<<dim3(512), 256, 0, stream>>>(
        ab, wot, ob0, BT, DMODEL, DMODEL, 0, DMODEL / 2, (size_t)BT * DMODEL);
    resnorm_k<<<BT, 256, 0, stream>>>(hb, ob0, ob1, w_attn, yb, 0);

    // FFN1: BN=256, GX=16, 512 blocks, plain row-major (R12: swizzle thrashed L2 on B)
    gemm_dbuf_k<256, 16, false><<<dim3(512), 256, 0, stream>>>(
        yb, w1t, midb, BT, FFDIM, DMODEL, 1, DMODEL, 0);
    // FFN2: GX=8, split-K=2 -> 512 blocks, XCD-swizzled (R12: improved)
    gemm_dbuf_k<128, 8, true><<<dim3(512), 256, 0, stream>>>(
        midb, w2t, fb0, BT, DMODEL, FFDIM, 0, FFDIM / 2, FB1_OFF);
    resnorm_k<<<BT, 256, 0, stream>>>(yb, fb0, fb1, w_ffn, d_out, 1);
}